// Round 13
// baseline (9774.216 us; speedup 1.0000x reference)
//
#include <hip/hip_runtime.h>

// GRU L=512, N=64, H=512, E=256, K=H+E=768. Persistent column-split kernel:
// 32 blocks x 256 threads; block b owns 16 output cols of z/r/h~; fp16 weight
// slices LDS-resident (73.7 KB, XOR-swizzled).
// Round 13: tagged-unit dataflow exchange (r5, correctness-verified) +
// SENTINEL discovery (fixes r5's full-panel repoll that caused 15.4ms):
//  - exchange unit: u64 = (generation tag << 32) | 2 packed fp16 cols,
//    stored with relaxed agent-scope atomics. Publication IS the data store:
//    no flags, no vmcnt drains in the loop (r4's 1.3us drain leg and 1.6us
//    flag leg deleted). Out-of-order store arrival is safe: every unit
//    carries its own tag.
//  - discovery: consumer wave w polls 2 sentinel units per producer block
//    (the block's last-stored units for rows 16w..16w+15): 16B/lane/iter,
//    vs r5's 512B/lane full-panel scan. After sentinels match, bulk-load
//    the 64-unit panel ONCE; exec-masked per-unit retry for stragglers
//    (r5's mechanism, now rare-case only).
//  - safety (r5-verified, unchanged): monotone tags; gen T+1 stores depend
//    via register dataflow on gen T loads (rh/h values are functions of the
//    full loaded panel), so transitively no unit is overwritten before all
//    its consumers read it. t=0 consumes memset tag 0 / data 0.
//  - e-prefetch double-buffered (aeA current / aeB next, issued mid-step);
//    out[t] written after the h publish (off the critical path).
// Numerics: fp16 operands, f32 MFMA accum, f32 state (absmax 3.9e-3 r1-r12).

#define LSTEPS 512
#define NBATCH 64
#define HDIM   512
#define EDIM   256
#define KDIM   768
#define NBLK   32
#define TPB    256

typedef _Float16 f16x8 __attribute__((ext_vector_type(8)));
typedef float    f32x4 __attribute__((ext_vector_type(4)));
typedef unsigned long long u64;

#define MFMA __builtin_amdgcn_mfma_f32_16x16x32_f16

__device__ __forceinline__ float sigm(float x){ return 1.0f/(1.0f+__expf(-x)); }
__device__ __forceinline__ float tanh_fast(float x){
  float e = __expf(2.0f*x);
  return 1.0f - 2.0f/(e + 1.0f);
}
__device__ __forceinline__ unsigned f16b(float x){
  union { _Float16 h; unsigned short u; } c; c.h = (_Float16)x; return (unsigned)c.u;
}

// Transpose+convert weights: wbuf[g][j][k] = fp16(W_g[k][j]); g in {z,r,h}.
__global__ void prep_w(const float* __restrict__ Wz, const float* __restrict__ Wr,
                       const float* __restrict__ Wh, _Float16* __restrict__ wbuf){
  int tid = blockIdx.x*256 + threadIdx.x;
  int g   = tid / (HDIM*KDIM);
  int rem = tid - g*(HDIM*KDIM);
  int j   = rem / KDIM;
  int k   = rem - j*KDIM;
  const float* W = (g==0) ? Wz : ((g==1) ? Wr : Wh);
  wbuf[tid] = (_Float16)W[(size_t)k*HDIM + j];
}

// Gather embedding rows + convert: ebuf[t][n][k] = fp16(emb[x[t][n]][k]).
__global__ void prep_emb(const int* __restrict__ x, const float* __restrict__ emb,
                         _Float16* __restrict__ ebuf){
  int tid = blockIdx.x*256 + threadIdx.x;
  int k4  = tid & 63;
  int tn  = tid >> 6;
  int row = x[tn];
  const float4 v = *(const float4*)(emb + (size_t)row*EDIM + (k4<<2));
  union { _Float16 h[4]; uint2 u; } p;
  p.h[0] = (_Float16)v.x; p.h[1] = (_Float16)v.y;
  p.h[2] = (_Float16)v.z; p.h[3] = (_Float16)v.w;
  *(uint2*)(ebuf + (size_t)tn*EDIM + (k4<<2)) = p.u;
}

// Tagged exchange store of (rows n0..n0+3, col jcol) -> [64][256] u64 units.
// Lane pair (2q,2q+1) covers cols (j,j+1): shfl_xor repack -> even lane
// stores rows n0..n0+1, odd lane rows n0+2..n0+3, each one 8B unit
// (hi32 = tag, lo32 = fp16 pair). Relaxed agent atomics -> coherence point.
__device__ __forceinline__ void store_tagged(u64* buf, int jc2u, int n0, int lane,
                                             unsigned tag,
                                             float v0, float v1, float v2, float v3){
  unsigned p01 = f16b(v0) | (f16b(v1) << 16);
  unsigned p23 = f16b(v2) | (f16b(v3) << 16);
  unsigned q01 = __shfl_xor(p01, 1, 64);
  unsigned q23 = __shfl_xor(p23, 1, 64);
  unsigned w0, w1; int r0;
  if (lane & 1){                       // own col = j+1 (high half of pair)
    w0 = (q23 & 0xffffu) | (p23 << 16);
    w1 = (q23 >> 16)     | (p23 & 0xffff0000u);
    r0 = n0 + 2;
  } else {                             // own col = j (low half)
    w0 = (p01 & 0xffffu) | (q01 << 16);
    w1 = (p01 >> 16)     | (q01 & 0xffff0000u);
    r0 = n0;
  }
  u64 t64 = ((u64)tag) << 32;
  __hip_atomic_store(buf + (size_t)r0*256 + jc2u,     t64 | (u64)w0,
                     __ATOMIC_RELAXED, __HIP_MEMORY_SCOPE_AGENT);
  __hip_atomic_store(buf + (size_t)(r0+1)*256 + jc2u, t64 | (u64)w1,
                     __ATOMIC_RELAXED, __HIP_MEMORY_SCOPE_AGENT);
}

__global__ __launch_bounds__(TPB, 1) void gru_persist(
    const _Float16* __restrict__ wbuf,   // [3][512][768]
    const _Float16* __restrict__ ebuf,   // [L][64][256]
    const float* __restrict__ bz, const float* __restrict__ br, const float* __restrict__ bh,
    u64* __restrict__ hx,                // [64][256] tagged h units
    u64* __restrict__ rhx,               // [64][256] tagged r*h units
    float* __restrict__ out)             // [L][64][512]
{
  __shared__ char wlds[3*16*1536];       // 73728 B
  const int jbase = blockIdx.x * 16;

  for (int cidx = threadIdx.x; cidx < 3*16*96; cidx += TPB){
    int g   = cidx / (16*96);
    int rem = cidx - g*(16*96);
    int col = rem / 96;
    int kch = rem - col*96;
    const uint4 v = *(const uint4*)(wbuf + ((size_t)(g*HDIM + jbase + col))*KDIM + kch*8);
    int off = (((g*16 + col)*1536) + kch*16) ^ ((col & 7) << 4);
    *(uint4*)(wlds + off) = v;
  }
  __syncthreads();                       // only barrier; loop below is per-wave

  const int lane = threadIdx.x & 63;
  const int wave = threadIdx.x >> 6;     // rows 16*wave..16*wave+15
  const int c15  = lane & 15;
  const int kgrp = lane >> 4;
  const int jcol = jbase + c15;
  const int jc2u = jcol >> 1;
  const int arow = wave*16 + c15;
  const int n0   = wave*16 + kgrp*4;
  const int swz  = (c15 & 7) << 4;
  const int linz = ((      c15)*1536) + kgrp*16;
  const int linr = ((16  + c15)*1536) + kgrp*16;
  const int linh = ((32  + c15)*1536) + kgrp*16;
  const float bzj = bz[jcol];
  const float brj = br[jcol];
  const float bhj = bh[jcol];
  const u64* hrow  = hx  + (size_t)arow*256 + kgrp*4;   // + kc*16 + i
  const u64* rhrow = rhx + (size_t)arow*256 + kgrp*4;
  // Sentinels: block (lane&31)'s LAST-stored units for this wave's rows
  // (row 16w+3, unit cols 8b and 8b+7 -- both are odd-lane second stores).
  const u64* hsent = hx  + (size_t)(wave*16 + 3)*256 + 8*(lane & 31);
  const u64* rsent = rhx + (size_t)(wave*16 + 3)*256 + 8*(lane & 31);
  float hreg[4] = {0.f, 0.f, 0.f, 0.f};

  u64 q[64];                              // tagged A-panel (128 VGPRs)
  f16x8 aeA[8], aeB[8];                   // e fragments: current / next step

  // Poll 2 sentinel units per producer block until tags match.
#define SENTWAIT(SB, TAG) do {                                                \
    for (;;){                                                                 \
      u64 s0 = __hip_atomic_load((SB),     __ATOMIC_RELAXED,                  \
                                 __HIP_MEMORY_SCOPE_AGENT);                   \
      u64 s1 = __hip_atomic_load((SB) + 7, __ATOMIC_RELAXED,                  \
                                 __HIP_MEMORY_SCOPE_AGENT);                   \
      unsigned bad = (((unsigned)(s0 >> 32)) ^ (TAG)) |                       \
                     (((unsigned)(s1 >> 32)) ^ (TAG));                        \
      if (!__any(bad != 0)) break;                                            \
    }                                                                         \
  } while (0)

  // Bulk load the 64-unit panel once (pipelined relaxed agent loads).
#define LOADQ(BASE) do {                                                      \
    _Pragma("unroll")                                                         \
    for (int kc = 0; kc < 16; ++kc){                                          \
      _Pragma("unroll")                                                       \
      for (int i = 0; i < 4; ++i)                                             \
        q[kc*4+i] = __hip_atomic_load((BASE) + kc*16 + i,                     \
                      __ATOMIC_RELAXED, __HIP_MEMORY_SCOPE_AGENT);            \
    }                                                                         \
  } while (0)

  // Straggler retry: reload ONLY stale units (rare after sentinel pass).
#define FIXQ(BASE, TAG) do {                                                  \
    for (;;){                                                                 \
      unsigned bad = 0;                                                       \
      _Pragma("unroll")                                                       \
      for (int j = 0; j < 64; ++j) bad |= ((unsigned)(q[j] >> 32)) ^ (TAG);   \
      if (!__any(bad != 0)) break;                                            \
      _Pragma("unroll")                                                       \
      for (int j = 0; j < 64; ++j){                                           \
        if ((unsigned)(q[j] >> 32) != (TAG))                                  \
          q[j] = __hip_atomic_load((BASE) + (j>>2)*16 + (j&3),                \
                   __ATOMIC_RELAXED, __HIP_MEMORY_SCOPE_AGENT);               \
      }                                                                       \
    }                                                                         \
  } while (0)

#define AFRAG(KC) ({ union { unsigned u[4]; f16x8 v; } _a;                    \
                     _a.u[0] = (unsigned)q[(KC)*4+0];                         \
                     _a.u[1] = (unsigned)q[(KC)*4+1];                         \
                     _a.u[2] = (unsigned)q[(KC)*4+2];                         \
                     _a.u[3] = (unsigned)q[(KC)*4+3]; _a.v; })

  // Prefetch e fragments for t = 0.
  {
    const _Float16* ae0 = ebuf + (size_t)arow*EDIM + kgrp*8;
    #pragma unroll
    for (int kc = 0; kc < 8; ++kc) aeA[kc] = *(const f16x8*)(ae0 + kc*32);
  }

  for (int t = 0; t < LSTEPS; ++t){
    const unsigned tago = (unsigned)t;        // h generation consumed
    const unsigned tagn = (unsigned)(t + 1);  // generation produced

    // ---- phase 1: r gate. e-part (regs) covers the sentinel wait.
    f32x4 accr = {0.f,0.f,0.f,0.f};
    #pragma unroll
    for (int kc = 0; kc < 8; ++kc){
      f16x8 brv = *(const f16x8*)(wlds + ((linr + (16+kc)*64) ^ swz));
      accr = MFMA(aeA[kc], brv, accr, 0, 0, 0);
    }
    SENTWAIT(hsent, tago);               // t=0: memset tags 0, passes
    LOADQ(hrow);
    FIXQ(hrow, tago);
    #pragma unroll
    for (int kc = 0; kc < 16; ++kc){
      f16x8 brv = *(const f16x8*)(wlds + ((linr + kc*64) ^ swz));
      accr = MFMA(AFRAG(kc), brv, accr, 0, 0, 0);
    }
    float rh[4];
    #pragma unroll
    for (int i = 0; i < 4; ++i)
      rh[i] = sigm(accr[i] + brj) * hreg[i];
    store_tagged(rhx, jc2u, n0, lane, tagn, rh[0], rh[1], rh[2], rh[3]);

    // ---- cover the rh flight: z (h frags in regs) + z,h~ e-parts + e(t+1).
    f32x4 accz = {0.f,0.f,0.f,0.f};
    f32x4 acch = {0.f,0.f,0.f,0.f};
    #pragma unroll
    for (int kc = 0; kc < 16; ++kc){
      f16x8 bzv = *(const f16x8*)(wlds + ((linz + kc*64) ^ swz));
      accz = MFMA(AFRAG(kc), bzv, accz, 0, 0, 0);
    }
    #pragma unroll
    for (int kc = 0; kc < 8; ++kc){
      f16x8 bzv = *(const f16x8*)(wlds + ((linz + (16+kc)*64) ^ swz));
      f16x8 bhv = *(const f16x8*)(wlds + ((linh + (16+kc)*64) ^ swz));
      accz = MFMA(aeA[kc], bzv, accz, 0, 0, 0);
      acch = MFMA(aeA[kc], bhv, acch, 0, 0, 0);
    }
    {                                    // e(t+1) prefetch into the free buffer
      const int tn = (t + 1 < LSTEPS) ? (t + 1) : t;
      const _Float16* aen = ebuf + ((size_t)tn*NBATCH + arow)*EDIM + kgrp*8;
      #pragma unroll
      for (int kc = 0; kc < 8; ++kc) aeB[kc] = *(const f16x8*)(aen + kc*32);
    }
    float zreg[4];
    #pragma unroll
    for (int i = 0; i < 4; ++i) zreg[i] = sigm(accz[i] + bzj);

    // ---- phase 2: h~ after the rh exchange; epilogue; publish h.
    SENTWAIT(rsent, tagn);
    LOADQ(rhrow);
    FIXQ(rhrow, tagn);
    #pragma unroll
    for (int kc = 0; kc < 16; ++kc){
      f16x8 bhv = *(const f16x8*)(wlds + ((linh + kc*64) ^ swz));
      acch = MFMA(AFRAG(kc), bhv, acch, 0, 0, 0);
    }
    #pragma unroll
    for (int i = 0; i < 4; ++i){
      float ht = tanh_fast(acch[i] + bhj);
      hreg[i] = hreg[i] + zreg[i]*(ht - hreg[i]);    // (1-z)h + z*h~
    }
    store_tagged(hx, jc2u, n0, lane, tagn, hreg[0], hreg[1], hreg[2], hreg[3]);

    // ---- off the critical path: out[t]; swap e buffers.
    #pragma unroll
    for (int i = 0; i < 4; ++i)
      out[((size_t)t*NBATCH + (n0+i))*HDIM + jcol] = hreg[i];
    #pragma unroll
    for (int kc = 0; kc < 8; ++kc) aeA[kc] = aeB[kc];
  }
#undef SENTWAIT
#undef LOADQ
#undef FIXQ
#undef AFRAG
}

extern "C" void kernel_launch(void* const* d_in, const int* in_sizes, int n_in,
                              void* d_out, int out_size, void* d_ws, size_t ws_size,
                              hipStream_t stream) {
  const int*   x   = (const int*)  d_in[0];
  const float* emb = (const float*)d_in[1];
  const float* Wz  = (const float*)d_in[2];
  const float* bz  = (const float*)d_in[3];
  const float* Wr  = (const float*)d_in[4];
  const float* br  = (const float*)d_in[5];
  const float* Wh  = (const float*)d_in[6];
  const float* bh  = (const float*)d_in[7];
  float* out = (float*)d_out;
  char*  ws  = (char*)d_ws;

  size_t off = 0;
  u64* hx  = (u64*)(ws + off); off += (size_t)NBATCH*(HDIM/2)*8;   // 131072
  u64* rhx = (u64*)(ws + off); off += (size_t)NBATCH*(HDIM/2)*8;   // 131072
  size_t zero_bytes = off;               // tags must start at 0 every launch
  _Float16* wbuf = (_Float16*)(ws + off); off += (size_t)3*HDIM*KDIM*2;        // 2359296
  _Float16* ebuf = (_Float16*)(ws + off); off += (size_t)LSTEPS*NBATCH*EDIM*2; // 16777216

  hipMemsetAsync(ws, 0, zero_bytes, stream);

  prep_w  <<<(3*HDIM*KDIM)/256,          256, 0, stream>>>(Wz, Wr, Wh, wbuf);
  prep_emb<<<(LSTEPS*NBATCH*EDIM/4)/256, 256, 0, stream>>>(x, emb, ebuf);
  gru_persist<<<NBLK, TPB, 0, stream>>>(wbuf, ebuf, bz, br, bh, hx, rhx, out);
}

// Round 14
// 5746.313 us; speedup vs baseline: 1.7010x; 1.7010x over previous
//
#include <hip/hip_runtime.h>

// GRU L=512, N=64, H=512, E=256, K=H+E=768. Persistent column-split kernel.
// Round 14 = round 4's proven per-wave-flag MALL protocol VERBATIM
// (relaxed agent-scope atomic exchange; producer: data stores -> vmcnt(0)
// drain -> per-block flag store; consumer: poll flags -> bulk atomic loads;
// the vmcnt(0) also retires prior-generation exchange loads => single-buffer
// safe) + three protocol-neutral wins never tested in isolation:
//  1. NBLK 16 x COLS 32 (147KB LDS weight slice, r10-proven geometry):
//     halves poll set, flag transactions, polling waves (64 vs 128) and
//     ebuf re-reads; doubles per-block cover compute.
//  2. double-buffered e-prefetch (aeA/aeB): e(t+1) issued right after the
//     rh publish, covered by z-matmul + rh-poll (~3us), consumed next step.
//  3. out[t] written AFTER the h flag publish (fire-and-forget; drains
//     during the next step's ~4us of cover+poll, off the critical vmcnt).
// History: protocols tried and beaten by r4 -- counter-RMW (r1/r8), tagged
// units (r3/r5/r13: no-drain publication loses to retry storms), graph
// launches (r6: 4.4us/launch), same-XCD L2 (r7/r11 hang, r10/r12 not
// faster). MALL store->load visibility RT ~1.3-1.6us; 3 legs/phase.
// Numerics: fp16 operands, f32 MFMA accum, f32 state (absmax 3.9e-3 r1-r13).

#define LSTEPS 512
#define NBATCH 64
#define HDIM   512
#define EDIM   256
#define KDIM   768
#define NBLK   16
#define COLS   32
#define TPB    256

typedef _Float16 f16x8 __attribute__((ext_vector_type(8)));
typedef float    f32x4 __attribute__((ext_vector_type(4)));
typedef unsigned long long u64;

#define MFMA __builtin_amdgcn_mfma_f32_16x16x32_f16

__device__ __forceinline__ float sigm(float x){ return 1.0f/(1.0f+__expf(-x)); }
__device__ __forceinline__ float tanh_fast(float x){
  float e = __expf(2.0f*x);
  return 1.0f - 2.0f/(e + 1.0f);
}
__device__ __forceinline__ unsigned f16b(float x){
  union { _Float16 h; unsigned short u; } c; c.h = (_Float16)x; return (unsigned)c.u;
}
__device__ __forceinline__ f16x8 AFU(u64 a, u64 b){
  union { u64 d[2]; f16x8 v; } c; c.d[0] = a; c.d[1] = b; return c.v;
}

// Transpose+convert weights: wbuf[g][j][k] = fp16(W_g[k][j]); g in {z,r,h}.
__global__ void prep_w(const float* __restrict__ Wz, const float* __restrict__ Wr,
                       const float* __restrict__ Wh, _Float16* __restrict__ wbuf){
  int tid = blockIdx.x*256 + threadIdx.x;
  int g   = tid / (HDIM*KDIM);
  int rem = tid - g*(HDIM*KDIM);
  int j   = rem / KDIM;
  int k   = rem - j*KDIM;
  const float* W = (g==0) ? Wz : ((g==1) ? Wr : Wh);
  wbuf[tid] = (_Float16)W[(size_t)k*HDIM + j];
}

// Gather embedding rows + convert: ebuf[t][n][k] = fp16(emb[x[t][n]][k]).
__global__ void prep_emb(const int* __restrict__ x, const float* __restrict__ emb,
                         _Float16* __restrict__ ebuf){
  int tid = blockIdx.x*256 + threadIdx.x;
  int k4  = tid & 63;
  int tn  = tid >> 6;
  int row = x[tn];
  const float4 v = *(const float4*)(emb + (size_t)row*EDIM + (k4<<2));
  union { _Float16 h[4]; uint2 u; } p;
  p.h[0] = (_Float16)v.x; p.h[1] = (_Float16)v.y;
  p.h[2] = (_Float16)v.z; p.h[3] = (_Float16)v.w;
  *(uint2*)(ebuf + (size_t)tn*EDIM + (k4<<2)) = p.u;
}

// Exchange store of (rows n0..n0+3, col jcol) as write-through 4B agent
// atomics. Lane pair (2q,2q+1) covers cols (j,j+1): shfl_xor repack ->
// even lane stores rows n0..n0+1, odd lane rows n0+2..n0+3, aligned dwords.
__device__ __forceinline__ void store_x(_Float16* buf, int jc2, int n0, int lane,
                                        float v0, float v1, float v2, float v3){
  unsigned p01 = f16b(v0) | (f16b(v1) << 16);
  unsigned p23 = f16b(v2) | (f16b(v3) << 16);
  unsigned q01 = __shfl_xor(p01, 1, 64);
  unsigned q23 = __shfl_xor(p23, 1, 64);
  unsigned w0, w1; int r0;
  if (lane & 1){                       // own col = j+1 (high half of pair)
    w0 = (q23 & 0xffffu) | (p23 << 16);
    w1 = (q23 >> 16)     | (p23 & 0xffff0000u);
    r0 = n0 + 2;
  } else {                             // own col = j (low half)
    w0 = (p01 & 0xffffu) | (q01 << 16);
    w1 = (p01 >> 16)     | (q01 & 0xffff0000u);
    r0 = n0;
  }
  __hip_atomic_store((unsigned*)(buf + (size_t)r0*HDIM + jc2),     w0,
                     __ATOMIC_RELAXED, __HIP_MEMORY_SCOPE_AGENT);
  __hip_atomic_store((unsigned*)(buf + (size_t)(r0+1)*HDIM + jc2), w1,
                     __ATOMIC_RELAXED, __HIP_MEMORY_SCOPE_AGENT);
}

// Poll 16 per-block flags (lane l polls flag[l&15]) until all >= target.
__device__ __forceinline__ void waitfl(const unsigned* fl, unsigned target){
  const int l15 = threadIdx.x & 15;
  for (;;){
    unsigned v = __hip_atomic_load(&fl[l15], __ATOMIC_RELAXED,
                                   __HIP_MEMORY_SCOPE_AGENT);
    if (__all(v >= target)) break;
  }
}

__global__ __launch_bounds__(TPB, 1) void gru_persist(
    const _Float16* __restrict__ wbuf,   // [3][512][768]
    const _Float16* __restrict__ ebuf,   // [L][64][256]
    const float* __restrict__ bz, const float* __restrict__ br, const float* __restrict__ bh,
    _Float16* __restrict__ hx,           // [64][512] fp16 exchange (h)
    _Float16* __restrict__ rhx,          // [64][512] fp16 exchange (r*h)
    unsigned* __restrict__ hfl,          // [4][16] per-wave h flags
    unsigned* __restrict__ rfl,          // [4][16] per-wave rh flags
    float* __restrict__ out)             // [L][64][512]
{
  __shared__ char wlds[3*COLS*1536];     // 147456 B
  const int jbase = blockIdx.x * COLS;

  // Stage weight slices -> LDS, XOR-swizzled by col to spread banks.
  for (int cidx = threadIdx.x; cidx < 3*COLS*96; cidx += TPB){
    int g   = cidx / (COLS*96);
    int rem = cidx - g*(COLS*96);
    int col = rem / 96;
    int kch = rem - col*96;
    const uint4 v = *(const uint4*)(wbuf + ((size_t)(g*HDIM + jbase + col))*KDIM + kch*8);
    int off = (((g*COLS + col)*1536) + kch*16) ^ ((col & 7) << 4);
    *(uint4*)(wlds + off) = v;
  }
  __syncthreads();                       // only barrier; loop below is per-wave

  const int lane = threadIdx.x & 63;
  const int wave = threadIdx.x >> 6;     // M-tile: rows 16*wave..16*wave+15
  const int c15  = lane & 15;
  const int kgrp = lane >> 4;
  const int arow = wave*16 + c15;
  const int n0   = wave*16 + kgrp*4;
  const int swz  = (c15 & 7) << 4;
  const int jcol0 = jbase + c15;
  const int jcol1 = jbase + 16 + c15;
  const int jc20  = jcol0 & ~1;
  const int jc21  = jcol1 & ~1;
  const int lz0 = ((0*COLS + c15     )*1536) + kgrp*16;
  const int lz1 = ((0*COLS + c15 + 16)*1536) + kgrp*16;
  const int lr0 = ((1*COLS + c15     )*1536) + kgrp*16;
  const int lr1 = ((1*COLS + c15 + 16)*1536) + kgrp*16;
  const int lh0 = ((2*COLS + c15     )*1536) + kgrp*16;
  const int lh1 = ((2*COLS + c15 + 16)*1536) + kgrp*16;
  const float bzj0 = bz[jcol0], bzj1 = bz[jcol1];
  const float brj0 = br[jcol0], brj1 = br[jcol1];
  const float bhj0 = bh[jcol0], bhj1 = bh[jcol1];
  unsigned* myhfl = hfl + wave*NBLK;     // this wave's row-group flag row
  unsigned* myrfl = rfl + wave*NBLK;
  const u64* hrow = (const u64*)hx  + (size_t)arow*128 + kgrp*2;   // + kc*8 (+1)
  const u64* rrow = (const u64*)rhx + (size_t)arow*128 + kgrp*2;
  float hreg0[4] = {0,0,0,0}, hreg1[4] = {0,0,0,0};

  u64 q[32];                             // one row-panel of A fragments
  f16x8 aeA[8], aeB[8];                  // e fragments: current / next step

#define LOADX(BASE) do {                                                      \
    _Pragma("unroll")                                                         \
    for (int kc = 0; kc < 16; ++kc){                                          \
      q[2*kc]   = __hip_atomic_load((BASE) + kc*8,     __ATOMIC_RELAXED,      \
                                    __HIP_MEMORY_SCOPE_AGENT);                \
      q[2*kc+1] = __hip_atomic_load((BASE) + kc*8 + 1, __ATOMIC_RELAXED,      \
                                    __HIP_MEMORY_SCOPE_AGENT);                \
    }                                                                         \
  } while (0)

  // Prefetch e fragments for t = 0.
  {
    const _Float16* ae0 = ebuf + (size_t)arow*EDIM + kgrp*8;
    #pragma unroll
    for (int kc = 0; kc < 8; ++kc) aeA[kc] = *(const f16x8*)(ae0 + kc*32);
  }

  for (int t = 0; t < LSTEPS; ++t){
    const unsigned tagn = (unsigned)(t + 1);

    // ---- phase 1: r gate. e-part first (regs, no stall), then h exchange.
    f32x4 accr0 = {0,0,0,0}, accr1 = {0,0,0,0};
    #pragma unroll
    for (int kc = 0; kc < 8; ++kc){
      f16x8 b0 = *(const f16x8*)(wlds + ((lr0 + (16+kc)*64) ^ swz));
      f16x8 b1 = *(const f16x8*)(wlds + ((lr1 + (16+kc)*64) ^ swz));
      accr0 = MFMA(aeA[kc], b0, accr0, 0, 0, 0);
      accr1 = MFMA(aeA[kc], b1, accr1, 0, 0, 0);
    }
    waitfl(myhfl, (unsigned)t);          // t=0: flags memset 0, passes; hx=0
    LOADX(hrow);
    #pragma unroll
    for (int kc = 0; kc < 16; ++kc){
      f16x8 a  = AFU(q[2*kc], q[2*kc+1]);
      f16x8 b0 = *(const f16x8*)(wlds + ((lr0 + kc*64) ^ swz));
      f16x8 b1 = *(const f16x8*)(wlds + ((lr1 + kc*64) ^ swz));
      accr0 = MFMA(a, b0, accr0, 0, 0, 0);
      accr1 = MFMA(a, b1, accr1, 0, 0, 0);
    }
    float rh0[4], rh1[4];
    #pragma unroll
    for (int i = 0; i < 4; ++i){
      rh0[i] = sigm(accr0[i] + brj0) * hreg0[i];
      rh1[i] = sigm(accr1[i] + brj1) * hreg1[i];
    }
    store_x(rhx, jc20, n0, lane, rh0[0], rh0[1], rh0[2], rh0[3]);
    store_x(rhx, jc21, n0, lane, rh1[0], rh1[1], rh1[2], rh1[3]);
    asm volatile("s_waitcnt vmcnt(0)" ::: "memory");   // rh stores + h loads drained
    __builtin_amdgcn_sched_barrier(0);
    if (lane == 0)
      __hip_atomic_store(&myrfl[blockIdx.x], tagn,
                         __ATOMIC_RELAXED, __HIP_MEMORY_SCOPE_AGENT);

    // ---- e(t+1) prefetch: covered by z-matmul + rh poll (~3us).
    {
      const int tn = (t + 1 < LSTEPS) ? (t + 1) : t;
      const _Float16* aen = ebuf + ((size_t)tn*NBATCH + arow)*EDIM + kgrp*8;
      #pragma unroll
      for (int kc = 0; kc < 8; ++kc) aeB[kc] = *(const f16x8*)(aen + kc*32);
    }

    // ---- cover the rh round-trip: z matmul (h frags in regs) + e-parts.
    f32x4 accz0 = {0,0,0,0}, accz1 = {0,0,0,0};
    f32x4 acch0 = {0,0,0,0}, acch1 = {0,0,0,0};
    #pragma unroll
    for (int kc = 0; kc < 16; ++kc){
      f16x8 a  = AFU(q[2*kc], q[2*kc+1]);
      f16x8 b0 = *(const f16x8*)(wlds + ((lz0 + kc*64) ^ swz));
      f16x8 b1 = *(const f16x8*)(wlds + ((lz1 + kc*64) ^ swz));
      accz0 = MFMA(a, b0, accz0, 0, 0, 0);
      accz1 = MFMA(a, b1, accz1, 0, 0, 0);
    }
    #pragma unroll
    for (int kc = 0; kc < 8; ++kc){
      f16x8 z0 = *(const f16x8*)(wlds + ((lz0 + (16+kc)*64) ^ swz));
      f16x8 z1 = *(const f16x8*)(wlds + ((lz1 + (16+kc)*64) ^ swz));
      f16x8 h0 = *(const f16x8*)(wlds + ((lh0 + (16+kc)*64) ^ swz));
      f16x8 h1 = *(const f16x8*)(wlds + ((lh1 + (16+kc)*64) ^ swz));
      accz0 = MFMA(aeA[kc], z0, accz0, 0, 0, 0);
      accz1 = MFMA(aeA[kc], z1, accz1, 0, 0, 0);
      acch0 = MFMA(aeA[kc], h0, acch0, 0, 0, 0);
      acch1 = MFMA(aeA[kc], h1, acch1, 0, 0, 0);
    }
    float zreg0[4], zreg1[4];
    #pragma unroll
    for (int i = 0; i < 4; ++i){
      zreg0[i] = sigm(accz0[i] + bzj0);
      zreg1[i] = sigm(accz1[i] + bzj1);
    }

    // ---- phase 2: h~ h-part after rh exchange; epilogue; publish h.
    waitfl(myrfl, tagn);
    LOADX(rrow);
    #pragma unroll
    for (int kc = 0; kc < 16; ++kc){
      f16x8 a  = AFU(q[2*kc], q[2*kc+1]);
      f16x8 b0 = *(const f16x8*)(wlds + ((lh0 + kc*64) ^ swz));
      f16x8 b1 = *(const f16x8*)(wlds + ((lh1 + kc*64) ^ swz));
      acch0 = MFMA(a, b0, acch0, 0, 0, 0);
      acch1 = MFMA(a, b1, acch1, 0, 0, 0);
    }
    #pragma unroll
    for (int i = 0; i < 4; ++i){
      float ht0 = tanh_fast(acch0[i] + bhj0);
      float ht1 = tanh_fast(acch1[i] + bhj1);
      hreg0[i] = hreg0[i] + zreg0[i]*(ht0 - hreg0[i]);   // (1-z)h + z*h~
      hreg1[i] = hreg1[i] + zreg1[i]*(ht1 - hreg1[i]);
    }
    store_x(hx, jc20, n0, lane, hreg0[0], hreg0[1], hreg0[2], hreg0[3]);
    store_x(hx, jc21, n0, lane, hreg1[0], hreg1[1], hreg1[2], hreg1[3]);
    asm volatile("s_waitcnt vmcnt(0)" ::: "memory");   // h stores + rh loads drained
    __builtin_amdgcn_sched_barrier(0);
    if (lane == 0)
      __hip_atomic_store(&myhfl[blockIdx.x], tagn,
                         __ATOMIC_RELAXED, __HIP_MEMORY_SCOPE_AGENT);

    // ---- off the critical path: out[t] (drains under next step's cover).
    #pragma unroll
    for (int i = 0; i < 4; ++i){
      int n = n0 + i;
      out[((size_t)t*NBATCH + n)*HDIM + jcol0] = hreg0[i];
      out[((size_t)t*NBATCH + n)*HDIM + jcol1] = hreg1[i];
    }
    #pragma unroll
    for (int kc = 0; kc < 8; ++kc) aeA[kc] = aeB[kc];
  }
#undef LOADX
}

extern "C" void kernel_launch(void* const* d_in, const int* in_sizes, int n_in,
                              void* d_out, int out_size, void* d_ws, size_t ws_size,
                              hipStream_t stream) {
  const int*   x   = (const int*)  d_in[0];
  const float* emb = (const float*)d_in[1];
  const float* Wz  = (const float*)d_in[2];
  const float* bz  = (const float*)d_in[3];
  const float* Wr  = (const float*)d_in[4];
  const float* br  = (const float*)d_in[5];
  const float* Wh  = (const float*)d_in[6];
  const float* bh  = (const float*)d_in[7];
  float* out = (float*)d_out;
  char*  ws  = (char*)d_ws;

  size_t off = 0;
  unsigned* hfl  = (unsigned*)(ws + off); off += 4*NBLK*4;                  // 256
  unsigned* rfl  = (unsigned*)(ws + off); off += 4*NBLK*4;                  // 256
  _Float16* hx   = (_Float16*)(ws + off); off += (size_t)NBATCH*HDIM*2;     // 65536
  size_t zero_bytes = off;               // flags + hx must start at 0
  _Float16* rhx  = (_Float16*)(ws + off); off += (size_t)NBATCH*HDIM*2;     // 65536
  _Float16* wbuf = (_Float16*)(ws + off); off += (size_t)3*HDIM*KDIM*2;     // 2359296
  _Float16* ebuf = (_Float16*)(ws + off); off += (size_t)LSTEPS*NBATCH*EDIM*2; // 16777216

  hipMemsetAsync(ws, 0, zero_bytes, stream);

  prep_w  <<<(3*HDIM*KDIM)/256,          256, 0, stream>>>(Wz, Wr, Wh, wbuf);
  prep_emb<<<(LSTEPS*NBATCH*EDIM/4)/256, 256, 0, stream>>>(x, emb, ebuf);
  gru_persist<<<NBLK, TPB, 0, stream>>>(wbuf, ebuf, bz, br, bh,
                                        hx, rhx, hfl, rfl, out);
}